// Round 2
// baseline (1025.009 us; speedup 1.0000x reference)
//
#include <hip/hip_runtime.h>

#define EPSF     1e-8f
#define LAMBF    0.5f
#define L2NORMF  1e-4f
#define NUSERS   100000
#define NITEMS   50000
#define EMB      64
#define RREL     3
#define NNZ_     1000000
#define IGNNZ    500000
#define BB       512
#define KK       100

// user -> batch slot map (any representative wins on duplicates; all reads
// go through the map so duplicates are consistent)
__global__ void scatter_user(const int* __restrict__ user, int* __restrict__ slot) {
    int b = blockIdx.x * blockDim.x + threadIdx.x;
    if (b < BB) slot[user[b]] = b;
}

// item-graph spmm: item_agg[row] += val * item_emb[col]; deg[row] += val
__global__ void ig_spmm(const int* __restrict__ rows, const int* __restrict__ cols,
                        const float* __restrict__ vals, const float* __restrict__ item_emb,
                        float* __restrict__ item_agg, float* __restrict__ ig_deg) {
    int lane = threadIdx.x & 63;
    int wave = (blockIdx.x * blockDim.x + threadIdx.x) >> 6;
    int nwaves = (gridDim.x * blockDim.x) >> 6;
    for (int e = wave; e < IGNNZ; e += nwaves) {
        int r = rows[e], c = cols[e];
        float v = vals[e];
        atomicAdd(&item_agg[r * EMB + lane], v * item_emb[c * EMB + lane]);
        if (lane == 0) atomicAdd(&ig_deg[r], v);
    }
}

// C[M x 64] = (A[M x 64] * rowscale) @ W[64 x 64]; rowscale = 1/(deg+EPS) or 1
__global__ void rowscale_matmul(const float* __restrict__ A, const float* __restrict__ deg,
                                const float* __restrict__ W, float* __restrict__ C, int M) {
    __shared__ float sW[64 * 64];
    __shared__ float sA[4][64];
    int tid = threadIdx.x;               // 256 threads
    for (int i = tid; i < 64 * 64; i += 256) sW[i] = W[i];
    int lr = tid >> 6, c = tid & 63;
    int row = blockIdx.x * 4 + lr;
    if (row < M) {
        float scale = deg ? 1.0f / (deg[row] + EPSF) : 1.0f;
        sA[lr][c] = A[row * 64 + c] * scale;
    }
    __syncthreads();
    if (row < M) {
        float out = 0.f;
#pragma unroll
        for (int k = 0; k < 64; k++) out += sA[lr][k] * sW[k * 64 + c];
        C[row * 64 + c] = out;
    }
}

// filtered relation scan: only edges whose user is in the batch contribute
__global__ void rel_scan(const int* __restrict__ rows, const int* __restrict__ cols,
                         const int* __restrict__ slot, const float* __restrict__ item_emb,
                         const float* __restrict__ item_prop2,
                         float* __restrict__ acc_neigh, float* __restrict__ acc_prop,
                         float* __restrict__ ubc) {
    int lane = threadIdx.x & 63;
    int wave = (blockIdx.x * blockDim.x + threadIdx.x) >> 6;
    int nwaves = (gridDim.x * blockDim.x) >> 6;
    for (int base = wave * 64; base < NNZ_; base += nwaves * 64) {
        int e = base + lane;
        int s = -1, c = 0;
        if (e < NNZ_) {
            s = slot[rows[e]];
            c = cols[e];
        }
        unsigned long long mask = __ballot(s >= 0);
        while (mask) {
            int j = __builtin_ctzll(mask);
            mask &= mask - 1;
            int bs = __shfl(s, j);
            int bc = __shfl(c, j);
            atomicAdd(&acc_neigh[bs * EMB + lane], item_emb[bc * EMB + lane]);
            atomicAdd(&acc_prop[bs * EMB + lane], item_prop2[bc * EMB + lane]);
            if (lane == 0) atomicAdd(&ubc[bs], 1.0f);
        }
    }
}

// per batch row: proj = (tmp_user_item_p[user[b]]) @ Wb, then
// score2[b,k] += dot(proj, [item_emb[it] | item_prop2[it]])
__global__ void proj_score2(const int* __restrict__ user, const int* __restrict__ slot,
                            const float* __restrict__ ubc, const float* __restrict__ acc_neigh,
                            const float* __restrict__ acc_prop, const float* __restrict__ Wb,
                            const int* __restrict__ item, const float* __restrict__ item_emb,
                            const float* __restrict__ item_prop2, float* __restrict__ score2) {
    int b = blockIdx.x;
    int tid = threadIdx.x;               // 256
    __shared__ float t[128];
    __shared__ float p[128];
    int rep = slot[user[b]];
    float inv = 1.0f / (ubc[rep] + EPSF);
    if (tid < 64)       t[tid] = acc_neigh[rep * 64 + tid] * inv;
    else if (tid < 128) t[tid] = acc_prop[rep * 64 + (tid - 64)] * inv;
    __syncthreads();
    if (tid < 128) {
        float o = 0.f;
#pragma unroll 8
        for (int k = 0; k < 128; k++) o += t[k] * Wb[k * 128 + tid];
        p[tid] = o;
    }
    __syncthreads();
    int wave = tid >> 6, lane = tid & 63;
    for (int k = wave; k < KK; k += 4) {
        int it = item[b * KK + k];
        float s = p[lane] * item_emb[it * 64 + lane] + p[64 + lane] * item_prop2[it * 64 + lane];
        for (int off = 32; off > 0; off >>= 1) s += __shfl_xor(s, off);
        if (lane == 0) score2[b * KK + k] += s;
    }
}

// item_feature[c] += user_emb[r] over train edges
__global__ void train_scatter(const int* __restrict__ trows, const int* __restrict__ tcols,
                              const float* __restrict__ user_emb, float* __restrict__ item_feat) {
    int lane = threadIdx.x & 63;
    int wave = (blockIdx.x * blockDim.x + threadIdx.x) >> 6;
    int nwaves = (gridDim.x * blockDim.x) >> 6;
    for (int e = wave; e < NNZ_; e += nwaves) {
        int r = trows[e], c = tcols[e];
        atomicAdd(&item_feat[c * EMB + lane], user_emb[r * EMB + lane]);
    }
}

// final: compute ufeat row + @W in-block, then score1 + LAMB*score2/R + l2
__global__ void final_k(const int* __restrict__ user, const int* __restrict__ item,
                        const int* __restrict__ slot, const float* __restrict__ ubc,
                        const float* __restrict__ acc_neigh, const float* __restrict__ mw,
                        const float* __restrict__ W, const float* __restrict__ user_emb,
                        const float* __restrict__ item_emb, const float* __restrict__ itf2,
                        const float* __restrict__ score2, float* __restrict__ out,
                        float* __restrict__ l2out) {
    int b = blockIdx.x;
    int tid = threadIdx.x;               // 256
    int wave = tid >> 6, lane = tid & 63;
    __shared__ float uf[64], u1[64], u2[64];
    __shared__ float red[4];
    int u = user[b];
    if (tid < 64) {
        int rep = slot[u];
        float w0 = mw[0], w1 = mw[1], w2 = mw[2];
        float c0 = ubc[0 * BB + rep], c1 = ubc[1 * BB + rep], c2 = ubc[2 * BB + rep];
        float invT = 1.0f / (c0 * w0 + c1 * w1 + c2 * w2 + EPSF);
        float f = (c0 * w0 * invT) / (c0 + EPSF) * acc_neigh[(0 * BB + rep) * 64 + tid]
                + (c1 * w1 * invT) / (c1 + EPSF) * acc_neigh[(1 * BB + rep) * 64 + tid]
                + (c2 * w2 * invT) / (c2 + EPSF) * acc_neigh[(2 * BB + rep) * 64 + tid];
        uf[tid] = f;
        u1[tid] = user_emb[u * 64 + tid];
    }
    __syncthreads();
    if (tid < 64) {
        float o = 0.f;
#pragma unroll
        for (int k = 0; k < 64; k++) o += uf[k] * W[k * 64 + tid];
        u2[tid] = o;
    }
    __syncthreads();
    float l2part = 0.f;
    for (int k = wave; k < KK; k += 4) {
        int it = item[b * KK + k];
        float e1 = item_emb[it * 64 + lane], e2 = itf2[it * 64 + lane];
        float s = u1[lane] * e1 + u2[lane] * e2;
        float q = e1 * e1 + e2 * e2;
        for (int off = 32; off > 0; off >>= 1) {
            s += __shfl_xor(s, off);
            q += __shfl_xor(q, off);
        }
        if (lane == 0) {
            out[b * KK + k] = s + LAMBF * (score2[b * KK + k] * (1.0f / (float)RREL));
            l2part += q;
        }
    }
    float su = u1[lane] * u1[lane] + u2[lane] * u2[lane];
    for (int off = 32; off > 0; off >>= 1) su += __shfl_xor(su, off);
    if (wave == 0 && lane == 0) l2part += (float)KK * su;
    if (lane == 0) red[wave] = l2part;
    __syncthreads();
    if (tid == 0) atomicAdd(l2out, L2NORMF * (red[0] + red[1] + red[2] + red[3]));
}

extern "C" void kernel_launch(void* const* d_in, const int* in_sizes, int n_in,
                              void* d_out, int out_size, void* d_ws, size_t ws_size,
                              hipStream_t stream) {
    const int*   user       = (const int*)d_in[0];
    const int*   item       = (const int*)d_in[1];
    const int*   rel_rows   = (const int*)d_in[2];
    const int*   rel_cols   = (const int*)d_in[3];
    const int*   ig_rows    = (const int*)d_in[4];
    const int*   ig_cols    = (const int*)d_in[5];
    const float* ig_vals    = (const float*)d_in[6];
    const int*   train_rows = (const int*)d_in[7];
    const int*   train_cols = (const int*)d_in[8];
    const float* user_emb   = (const float*)d_in[9];
    const float* item_emb   = (const float*)d_in[10];
    const float* mw         = (const float*)d_in[11];
    const float* Wb         = (const float*)d_in[12];  // R x 128 x 128
    const float* Wp         = (const float*)d_in[13];  // R x 64 x 64
    const float* W          = (const float*)d_in[14];  // 64 x 64
    float* out = (float*)d_out;

    // ---- workspace layout (floats) ----
    float* ws = (float*)d_ws;
    size_t o = 0;
    int*   user_slot  = (int*)(ws + o); o += NUSERS;
    float* item_agg   = ws + o; o += (size_t)NITEMS * 64;   // reused as item_feat in end phase
    float* ig_deg     = ws + o; o += NITEMS;                // contiguous after item_agg (one memset)
    float* item_prop2 = ws + o; o += (size_t)NITEMS * 64;   // reused as itf2 in end phase
    // contiguous zero zone:
    float* acc_neigh  = ws + o; o += (size_t)RREL * BB * 64;
    float* acc_prop   = ws + o; o += (size_t)RREL * BB * 64;
    float* ubc        = ws + o; o += (size_t)RREL * BB;
    float* score2     = ws + o; o += (size_t)BB * KK;
    size_t need_bytes = o * sizeof(float);
    if (ws_size < need_bytes) return;   // undersized scratch: bail cleanly (no OOB)

    size_t zero_zone = (size_t)RREL * BB * 64 * 2 + RREL * BB + BB * KK;

    // phase 0: init
    hipMemsetAsync(user_slot, 0xFF, (size_t)NUSERS * 4, stream);           // = -1
    scatter_user<<<2, 256, 0, stream>>>(user, user_slot);
    hipMemsetAsync(acc_neigh, 0, zero_zone * 4, stream);
    hipMemsetAsync(out + (out_size - 1), 0, 4, stream);                    // l2 slot

    // per-relation phase
    for (int i = 0; i < RREL; i++) {
        hipMemsetAsync(item_agg, 0, ((size_t)NITEMS * 64 + NITEMS) * 4, stream); // item_agg + ig_deg
        ig_spmm<<<2048, 256, 0, stream>>>(ig_rows + (size_t)i * IGNNZ, ig_cols + (size_t)i * IGNNZ,
                                          ig_vals + (size_t)i * IGNNZ, item_emb, item_agg, ig_deg);
        rowscale_matmul<<<(NITEMS + 3) / 4, 256, 0, stream>>>(item_agg, ig_deg,
                                                              Wp + (size_t)i * 64 * 64, item_prop2, NITEMS);
        rel_scan<<<2048, 256, 0, stream>>>(rel_rows + (size_t)i * NNZ_, rel_cols + (size_t)i * NNZ_,
                                           user_slot, item_emb, item_prop2,
                                           acc_neigh + (size_t)i * BB * 64,
                                           acc_prop + (size_t)i * BB * 64, ubc + (size_t)i * BB);
        proj_score2<<<BB, 256, 0, stream>>>(user, user_slot, ubc + (size_t)i * BB,
                                            acc_neigh + (size_t)i * BB * 64,
                                            acc_prop + (size_t)i * BB * 64,
                                            Wb + (size_t)i * 128 * 128,
                                            item, item_emb, item_prop2, score2);
    }

    // end phase: item_feat reuses item_agg buffer; itf2 reuses item_prop2 buffer
    float* item_feat = item_agg;
    float* itf2      = item_prop2;
    hipMemsetAsync(item_feat, 0, (size_t)NITEMS * 64 * 4, stream);
    train_scatter<<<4096, 256, 0, stream>>>(train_rows, train_cols, user_emb, item_feat);
    rowscale_matmul<<<(NITEMS + 3) / 4, 256, 0, stream>>>(item_feat, nullptr, W, itf2, NITEMS);
    final_k<<<BB, 256, 0, stream>>>(user, item, user_slot, ubc, acc_neigh, mw, W,
                                    user_emb, item_emb, itf2, score2,
                                    out, out + (out_size - 1));
}